// Round 10
// baseline (1137.365 us; speedup 1.0000x reference)
//
#include <hip/hip_runtime.h>
#include <hip/hip_bf16.h>
#include <cstdint>

// MHRetention: x[4,4096,2048] ; Wq,Wk,Wv,Wu,Wo [2048,2048] (stored [in,out])
// q,k = relu(xW)/sqrt(128); u = silu(xWu); kv = sum_l k^T v per (b,h);
// o = srms_norm(q @ kv) * u ; y = o @ Wo
// N=16384 tokens, D=2048, H=16, dh=128.

typedef __attribute__((ext_vector_type(8))) short short8;
typedef __attribute__((ext_vector_type(4))) float f32x4;

#define DEVI static __device__ __forceinline__

DEVI float bf2f(unsigned short u) {
    union { unsigned int i; float f; } w; w.i = ((unsigned int)u) << 16; return w.f;
}
DEVI unsigned short f2bf(float f) {
    union { float f; unsigned int i; } w; w.f = f;
    return (unsigned short)((w.i + 0x7fffu + ((w.i >> 16) & 1u)) >> 16);  // RNE
}

// global -> LDS direct DMA, 16B per lane. LDS dest is wave-uniform base + lane*16.
#define GLDS16(gp, lp) __builtin_amdgcn_global_load_lds( \
    (const __attribute__((address_space(1))) void*)(gp), \
    (__attribute__((address_space(3))) void*)(lp), 16, 0, 0)

// ---------------------------------------------------------------- dtype probe
__global__ void probe_dtype(const unsigned short* __restrict__ x, int* flag) {
    __shared__ int cnt;
    if (threadIdx.x == 0) cnt = 0;
    __syncthreads();
    int c = 0;
    for (int i = threadIdx.x; i < 4096; i += 256) {
        float a = fabsf(bf2f(x[i]));
        if (!(a <= 1e4f) || (a != 0.0f && a < 1e-4f)) ++c;
    }
    atomicAdd(&cnt, c);
    __syncthreads();
    if (threadIdx.x == 0) *flag = (cnt < 512) ? 1 : 0;
}

// ------------------------------------------------- weight transpose + convert
__global__ void wconvert(const void* __restrict__ Wq, const void* __restrict__ Wk,
                         const void* __restrict__ Wv, const void* __restrict__ Wu,
                         const void* __restrict__ Wo,
                         unsigned short* __restrict__ wt4,
                         unsigned short* __restrict__ wot,
                         const int* __restrict__ flag) {
    const int z = blockIdx.z;
    const void* W = (z == 0) ? Wq : (z == 1) ? Wk : (z == 2) ? Wv : (z == 3) ? Wu : Wo;
    const bool isbf = (*flag != 0);
    __shared__ float tile[32][33];
    const int j0 = blockIdx.x * 32, i0 = blockIdx.y * 32;
    const int tx = threadIdx.x, ty = threadIdx.y;  // (32,8)
#pragma unroll
    for (int r = 0; r < 4; ++r) {
        const int i = i0 + ty * 4 + r;
        float v;
        if (isbf) v = bf2f(((const unsigned short*)W)[i * 2048 + j0 + tx]);
        else      v = ((const float*)W)[i * 2048 + j0 + tx];
        tile[ty * 4 + r][tx] = v;
    }
    __syncthreads();
#pragma unroll
    for (int r = 0; r < 4; ++r) {
        const int j = j0 + ty * 4 + r;
        const unsigned short bv = f2bf(tile[tx][ty * 4 + r]);  // = W[i0+tx][j]
        if (z < 4) wt4[(long)(z * 2048 + j) * 2048 + i0 + tx] = bv;
        else       wot[(long)j * 2048 + i0 + tx] = bv;
    }
}

// ------------------------------------------------------------- x -> bf16
__global__ void xconvert(const void* __restrict__ X, unsigned short* __restrict__ xb,
                         const int* __restrict__ flag) {
    const bool isbf = (*flag != 0);
    const long i = (long)blockIdx.x * 256 + threadIdx.x;
    if (isbf) {
        ((uint4*)xb)[i] = ((const uint4*)X)[i];
    } else {
        const float4 f0 = ((const float4*)X)[2 * i];
        const float4 f1 = ((const float4*)X)[2 * i + 1];
        union { unsigned short us[8]; uint4 v; } o;
        o.us[0] = f2bf(f0.x); o.us[1] = f2bf(f0.y); o.us[2] = f2bf(f0.z); o.us[3] = f2bf(f0.w);
        o.us[4] = f2bf(f1.x); o.us[5] = f2bf(f1.y); o.us[6] = f2bf(f1.z); o.us[7] = f2bf(f1.w);
        ((uint4*)xb)[i] = o.v;
    }
}

// ---------------------------------------------------------------------------
// 128x128 GEMM core (R10): R5's reg-dbuf counted-vmcnt pipeline at 4 waves,
// ring-3 LDS (48KB) -> 3 blocks/CU, 3 waves/SIMD. Independent co-resident
// blocks provide the latency hiding the 2-wave lockstep lacked.
// Per K-tile per wave: 4 glds + 8 ds_read_b128 + 16 MFMA.
// Ledger: prologue ISSUE(0,1,2)=12 loads; body t: {vmcnt(8) [tile t+1
// resident, 2 tiles in flight]; barrier; RDFRAG(t+1 -> other bank);
// lgkmcnt(8); ISSUE(t+3, wrap -63 preserves buf == t mod 3); 16 MFMA}.
// T2 slot-XOR swizzle both sides (same algebra as R5, conflict-free).
// ---------------------------------------------------------------------------
DEVI void gemm_core(const unsigned short* __restrict__ Ag,   // + m0*2048
                    const unsigned short* __restrict__ Bg,   // + j0*2048
                    unsigned short* As, unsigned short* Bs,  // [3*4096] ushorts each
                    f32x4 acc[4][4], const int tid) {
    const int wave = tid >> 6, lane = tid & 63;
    const int wr = wave >> 1, wc = wave & 1;
    // staging: wave w covers rows [w*32, w*32+32) in 2 issues of 16 rows
    const int srow = wave * 32 + (lane >> 2);        // issue-0 row
    const int lsl = (lane & 3) ^ ((srow >> 1) & 3);  // swizzled logical slot
    const unsigned short* ga0 = Ag + (long)srow * 2048 + lsl * 8;
    const unsigned short* ga1 = ga0 + 16 * 2048;
    const unsigned short* gb0 = Bg + (long)srow * 2048 + lsl * 8;
    const unsigned short* gb1 = gb0 + 16 * 2048;
    const int ldsb = wave * 1024;                    // ushort offset of wave's chunk

    // read side: physical slot = (lane>>4) ^ ((row>>1)&3); row-parity bits
    // depend only on (lane&15)>>1 (wr*64 and fm*16 are 0 mod 4 after >>1)
    const int psl = ((lane >> 4) ^ (((lane & 15) >> 1) & 3)) * 8;
    const int abase = (wr * 64 + (lane & 15)) * 32 + psl;
    const int bbase = (wc * 64 + (lane & 15)) * 32 + psl;

#define ISSUE(tt) do { const int _b = (tt) % 3; const int _ko = (tt) * 32; \
    GLDS16(ga0 + _ko, As + _b * 4096 + ldsb); \
    GLDS16(ga1 + _ko, As + _b * 4096 + 512 + ldsb); \
    GLDS16(gb0 + _ko, Bs + _b * 4096 + ldsb); \
    GLDS16(gb1 + _ko, Bs + _b * 4096 + 512 + ldsb); } while (0)
#define RDFRAG(aX, bX, buf) do { \
    const unsigned short* _a = As + (buf) * 4096; \
    const unsigned short* _b = Bs + (buf) * 4096; \
    _Pragma("unroll") for (int f = 0; f < 4; ++f) aX[f] = *(const short8*)(_a + abase + f * 512); \
    _Pragma("unroll") for (int f = 0; f < 4; ++f) bX[f] = *(const short8*)(_b + bbase + f * 512); } while (0)
#define MFMACL(aX, bX) do { \
    __builtin_amdgcn_s_setprio(1); \
    _Pragma("unroll") for (int fm = 0; fm < 4; ++fm) \
    _Pragma("unroll") for (int fn = 0; fn < 4; ++fn) \
        acc[fm][fn] = __builtin_amdgcn_mfma_f32_16x16x32_bf16(aX[fm], bX[fn], acc[fm][fn], 0, 0, 0); \
    __builtin_amdgcn_s_setprio(0); } while (0)

    ISSUE(0); ISSUE(1); ISSUE(2);                    // 12 loads outstanding
    asm volatile("s_waitcnt vmcnt(8)" ::: "memory");  // tile 0 resident
    asm volatile("s_barrier" ::: "memory");
    short8 aE[4], bE[4], aO[4], bO[4];
    RDFRAG(aE, bE, 0);                               // tile 0 -> even bank

    for (int tp = 0; tp < 32; ++tp) {
        const int t = 2 * tp;
        // ---- even body: compute tile t (E); read t+1 -> O; issue t+3
        asm volatile("s_waitcnt vmcnt(8)" ::: "memory");   // tile t+1 resident
        asm volatile("s_barrier" ::: "memory");            // all waves' DMA visible
        RDFRAG(aO, bO, (t + 1) % 3);
        asm volatile("s_waitcnt lgkmcnt(8)" ::: "memory"); // tile-t frags in regs
        { int ti = t + 3; if (ti >= 64) ti -= 63; ISSUE(ti); }  // buf == t%3 (free)
        MFMACL(aE, bE);
        // ---- odd body: compute tile t+1 (O); read t+2 -> E; issue t+4
        asm volatile("s_waitcnt vmcnt(8)" ::: "memory");   // tile t+2 resident
        asm volatile("s_barrier" ::: "memory");
        { int tr = t + 2; if (tr > 63) tr = 63; RDFRAG(aE, bE, tr % 3); }
        asm volatile("s_waitcnt lgkmcnt(8)" ::: "memory");
        { int ti = t + 4; if (ti >= 64) ti -= 63; ISSUE(ti); }  // buf == (t+1)%3
        MFMACL(aO, bO);
    }
    asm volatile("s_waitcnt vmcnt(0) lgkmcnt(0)" ::: "memory");  // drain dead tails
#undef ISSUE
#undef RDFRAG
#undef MFMACL
}

// ---------------------------------------------- fused QKVU projection GEMM
__global__ __launch_bounds__(256, 3)
void gemm_qkvu(const unsigned short* __restrict__ Xb,
               const unsigned short* __restrict__ Wt4,
               unsigned short* __restrict__ Qb, unsigned short* __restrict__ Kb,
               unsigned short* __restrict__ Vb, unsigned short* __restrict__ Ub) {
    __shared__ unsigned short As[3 * 4096];
    __shared__ unsigned short Bs[3 * 4096];
    const int orig = blockIdx.x;                       // 0..8191
    const int flat = (orig & 7) * 1024 + (orig >> 3);  // XCD owns 8 B-panels, m-fastest
    const int mt = flat & 127, nt = flat >> 7;         // 128 m-tiles, 64 n-tiles
    const long m0 = (long)mt * 128;
    const int tid = threadIdx.x;
    f32x4 acc[4][4] = {};

    gemm_core(Xb + m0 * 2048, Wt4 + (long)nt * 128 * 2048, As, Bs, acc, tid);

    const int wave = tid >> 6, lane = tid & 63;
    const int wr = wave >> 1, wc = wave & 1;
    const int seg = nt >> 4;                           // 0..3 -> Q,K,V,U
    unsigned short* outp = (seg == 0) ? Qb : (seg == 1) ? Kb : (seg == 2) ? Vb : Ub;
    const int cl0 = (nt & 15) * 128 + wc * 64;
#pragma unroll
    for (int fm = 0; fm < 4; ++fm) {
#pragma unroll
        for (int fn = 0; fn < 4; ++fn) {
            const int col = cl0 + fn * 16 + (lane & 15);
#pragma unroll
            for (int r = 0; r < 4; ++r) {
                const long row = m0 + wr * 64 + fm * 16 + ((lane >> 4) << 2) + r;
                float v = acc[fm][fn][r];
                if (seg <= 1)      v = fmaxf(v, 0.0f) * 0.08838834764831845f;  // relu/sqrt(128)
                else if (seg == 3) v = v / (1.0f + __expf(-v));                // silu
                outp[row * 2048 + col] = f2bf(v);
            }
        }
    }
}

// ------------------------------------------------------- output projection
__global__ __launch_bounds__(256, 3)
void gemm_out(const unsigned short* __restrict__ Obuf,
              const unsigned short* __restrict__ Wot,
              void* __restrict__ out, const int* __restrict__ flag) {
    __shared__ unsigned short As[3 * 4096];
    __shared__ unsigned short Bs[3 * 4096];
    const int orig = blockIdx.x;                       // 0..2047
    const int flat = (orig & 7) * 256 + (orig >> 3);   // XCD owns 2 B-panels
    const int mt = flat & 127, nt = flat >> 7;         // 128 m-tiles, 16 n-tiles
    const long m0 = (long)mt * 128;
    const int j0 = nt * 128;
    const int tid = threadIdx.x;
    f32x4 acc[4][4] = {};

    gemm_core(Obuf + m0 * 2048, Wot + (long)j0 * 2048, As, Bs, acc, tid);

    const int wave = tid >> 6, lane = tid & 63;
    const int wr = wave >> 1, wc = wave & 1;
    const bool isbf = (*flag != 0);
#pragma unroll
    for (int fm = 0; fm < 4; ++fm) {
#pragma unroll
        for (int fn = 0; fn < 4; ++fn) {
            const int col = j0 + wc * 64 + fn * 16 + (lane & 15);
#pragma unroll
            for (int r = 0; r < 4; ++r) {
                const long row = m0 + wr * 64 + fm * 16 + ((lane >> 4) << 2) + r;
                const float v = acc[fm][fn][r];
                if (isbf) ((unsigned short*)out)[row * 2048 + col] = f2bf(v);
                else      ((float*)out)[row * 2048 + col] = v;
            }
        }
    }
}

// --------------------------------------------- KV state via MFMA
// KVt[dv][dk] = sum_l V[l,dv]*K[l,dk] per (b,h).  A=V^T, B=K^T staged
// transposed in LDS (XOR-swizzled), bf16 MFMA fp32 acc (products exact).
__global__ void kv_accum(const unsigned short* __restrict__ Kb,
                         const unsigned short* __restrict__ Vb,
                         float* __restrict__ KVpart) {
    __shared__ unsigned short Kt[128 * 64];  // [dk][l], swizzled
    __shared__ unsigned short Vt[128 * 64];  // [dv][l], swizzled
    const int bh = blockIdx.x;      // 64
    const int chunk = blockIdx.y;   // 4 chunks of 1024 rows
    const int b = bh >> 4, h = bh & 15;
    const int t = threadIdx.x, wave = t >> 6, lane = t & 63;
    const int wr = wave >> 1, wc = wave & 1;
    const int l0 = (t & 15) * 4;
    const int dkg = t >> 4;
    const long gbase = ((long)b * 4096 + chunk * 1024) * 2048 + h * 128;
    f32x4 acc[4][4] = {};

    for (int tile = 0; tile < 16; ++tile) {
        __syncthreads();
        short8 kr[4], vr[4];
#pragma unroll
        for (int li = 0; li < 4; ++li) {
            const long go = gbase + (long)(tile * 64 + l0 + li) * 2048 + dkg * 8;
            kr[li] = *(const short8*)(Kb + go);
            vr[li] = *(const short8*)(Vb + go);
        }
#pragma unroll
        for (int i = 0; i < 8; ++i) {
            const int row = dkg * 8 + i;
            const int lin = row * 128 + l0 * 2;
            const int off = (lin ^ ((row & 7) << 4)) >> 1;
            union { unsigned short us[4]; unsigned long long u; } pk, pv;
#pragma unroll
            for (int li = 0; li < 4; ++li) { pk.us[li] = (unsigned short)kr[li][i]; pv.us[li] = (unsigned short)vr[li][i]; }
            *(unsigned long long*)(Kt + off) = pk.u;
            *(unsigned long long*)(Vt + off) = pv.u;
        }
        __syncthreads();
#pragma unroll
        for (int ks = 0; ks < 2; ++ks) {
            const int kof = ks * 64 + (lane >> 4) * 16;
            short8 a[4], bfr[4];
#pragma unroll
            for (int f = 0; f < 4; ++f) {
                const int ra = wr * 64 + f * 16 + (lane & 15);
                const int rb = wc * 64 + f * 16 + (lane & 15);
                a[f]   = *(const short8*)(Vt + (((ra * 128 + kof) ^ ((ra & 7) << 4)) >> 1));
                bfr[f] = *(const short8*)(Kt + (((rb * 128 + kof) ^ ((rb & 7) << 4)) >> 1));
            }
#pragma unroll
            for (int fm = 0; fm < 4; ++fm)
#pragma unroll
                for (int fn = 0; fn < 4; ++fn)
                    acc[fm][fn] = __builtin_amdgcn_mfma_f32_16x16x32_bf16(a[fm], bfr[fn], acc[fm][fn], 0, 0, 0);
        }
    }
    float* dst = KVpart + ((long)chunk * 64 + bh) * 16384;
#pragma unroll
    for (int fm = 0; fm < 4; ++fm)
#pragma unroll
        for (int fn = 0; fn < 4; ++fn)
#pragma unroll
            for (int r = 0; r < 4; ++r) {
                const int dv = wr * 64 + fm * 16 + ((lane >> 4) << 2) + r;
                const int dk = wc * 64 + fn * 16 + (lane & 15);
                dst[dv * 128 + dk] = acc[fm][fn][r];
            }
}

// ------------------------------- sum partials, emit bf16 KV (hi only)
__global__ void kv_finalize(const float* __restrict__ KVpart,
                            unsigned short* __restrict__ KVhi) {
    const long base = ((long)blockIdx.x * 256 + threadIdx.x) * 4;
    float4 s0 = *(const float4*)(KVpart + base);
    const float4 s1 = *(const float4*)(KVpart + 1048576 + base);
    const float4 s2 = *(const float4*)(KVpart + 2097152 + base);
    const float4 s3 = *(const float4*)(KVpart + 3145728 + base);
    float s[4] = { s0.x + s1.x + s2.x + s3.x, s0.y + s1.y + s2.y + s3.y,
                   s0.z + s1.z + s2.z + s3.z, s0.w + s1.w + s2.w + s3.w };
    union { unsigned short us[4]; unsigned long long u; } hi;
#pragma unroll
    for (int j = 0; j < 4; ++j) hi.us[j] = f2bf(s[j]);
    *(unsigned long long*)(KVhi + base) = hi.u;
}

// ------------------------- O = Q @ KV, SRMS-norm over dh, * u, -> bf16 Ob
__global__ void o_norm(const unsigned short* __restrict__ Qb,
                       const unsigned short* __restrict__ Ub,
                       const unsigned short* __restrict__ KVhi,
                       unsigned short* __restrict__ Ob) {
    __shared__ unsigned short Qs[128 * 128];
    const int tid = threadIdx.x, wave = tid >> 6, lane = tid & 63;
    const int tile = blockIdx.x;   // 0..31
    const int bh = blockIdx.y;     // 0..63
    const int b = bh >> 4, h = bh & 15;
    const long n0 = (long)b * 4096 + tile * 128;

    const int qrow = tid >> 4;
    const int qcol = (tid & 15) * 8;
#pragma unroll
    for (int i = 0; i < 8; ++i)
        GLDS16(Qb + (n0 + i * 16 + qrow) * 2048 + h * 128 + qcol, Qs + i * 2048 + wave * 512);
    __syncthreads();

    const unsigned short* KH = KVhi + (long)bh * 16384;
    f32x4 acc[2][8] = {};
#pragma unroll
    for (int kk = 0; kk < 4; ++kk) {
        const short8 a0 = *(const short8*)(Qs + (wave * 32 + (lane & 15)) * 128 + kk * 32 + (lane >> 4) * 8);
        const short8 a1 = *(const short8*)(Qs + (wave * 32 + 16 + (lane & 15)) * 128 + kk * 32 + (lane >> 4) * 8);
#pragma unroll
        for (int fn = 0; fn < 8; ++fn) {
            const int bo = (fn * 16 + (lane & 15)) * 128 + kk * 32 + (lane >> 4) * 8;
            const short8 bhi = *(const short8*)(KH + bo);
            acc[0][fn] = __builtin_amdgcn_mfma_f32_16x16x32_bf16(a0, bhi, acc[0][fn], 0, 0, 0);
            acc[1][fn] = __builtin_amdgcn_mfma_f32_16x16x32_bf16(a1, bhi, acc[1][fn], 0, 0, 0);
        }
    }

#pragma unroll
    for (int fm = 0; fm < 2; ++fm) {
#pragma unroll
        for (int r = 0; r < 4; ++r) {
            float ssq = 0.0f;
#pragma unroll
            for (int fn = 0; fn < 8; ++fn) { const float v = acc[fm][fn][r]; ssq += v * v; }
            ssq += __shfl_xor(ssq, 1);
            ssq += __shfl_xor(ssq, 2);
            ssq += __shfl_xor(ssq, 4);
            ssq += __shfl_xor(ssq, 8);
            const float nrm = fmaxf(sqrtf(ssq) * 0.08838834764831845f, 1e-12f);
            const float scl = 1.0f / nrm;
            const long row = n0 + wave * 32 + fm * 16 + ((lane >> 4) << 2) + r;
#pragma unroll
            for (int fn = 0; fn < 8; ++fn) {
                const int col = fn * 16 + (lane & 15);
                const float uv = bf2f(Ub[row * 2048 + h * 128 + col]);
                Ob[row * 2048 + h * 128 + col] = f2bf(acc[fm][fn][r] * scl * uv);
            }
        }
    }
}

// ---------------------------------------------------------------- launcher
extern "C" void kernel_launch(void* const* d_in, const int* in_sizes, int n_in,
                              void* d_out, int out_size, void* d_ws, size_t ws_size,
                              hipStream_t stream) {
    (void)in_sizes; (void)n_in; (void)out_size; (void)ws_size;
    char* ws = (char*)d_ws;
    unsigned short* Xb  = (unsigned short*)(ws + 0);           // 64 MB
    unsigned short* Wt4 = (unsigned short*)(ws + 67108864);    // 32 MB
    unsigned short* Wot = (unsigned short*)(ws + 100663296);   //  8 MB
    unsigned short* Qb  = (unsigned short*)(ws + 109051904);   // 64 MB
    unsigned short* Kb  = (unsigned short*)(ws + 176160768);   // 64 MB
    unsigned short* Vb  = (unsigned short*)(ws + 243269632);   // 64 MB
    unsigned short* Ub  = (unsigned short*)(ws + 310378496);   // 64 MB
    int*            flag= (int*)(ws + 381681664);              //  4 B
    // regions reused after their producers are done:
    float*          KVpart = (float*)Wt4;                       // 16 MB (Wt4 dead after gemm_qkvu)
    unsigned short* KVhi   = (unsigned short*)(ws + 67108864 + 16777216);  // 2 MB
    unsigned short* Ob     = Xb;                                // Xb dead after gemm_qkvu

    probe_dtype<<<1, 256, 0, stream>>>((const unsigned short*)d_in[0], flag);
    wconvert<<<dim3(64, 64, 5), dim3(32, 8), 0, stream>>>(d_in[1], d_in[2], d_in[3],
                                                          d_in[4], d_in[5], Wt4, Wot, flag);
    xconvert<<<16384, 256, 0, stream>>>(d_in[0], Xb, flag);
    gemm_qkvu<<<8192, 256, 0, stream>>>(Xb, Wt4, Qb, Kb, Vb, Ub);
    kv_accum<<<dim3(64, 4), 256, 0, stream>>>(Kb, Vb, KVpart);
    kv_finalize<<<1024, 256, 0, stream>>>(KVpart, KVhi);
    o_norm<<<dim3(32, 64), 256, 0, stream>>>(Qb, Ub, KVhi, Ob);
    gemm_out<<<2048, 256, 0, stream>>>(Ob, Wot, d_out, flag);
}

// Round 11
// 992.976 us; speedup vs baseline: 1.1454x; 1.1454x over previous
//
#include <hip/hip_runtime.h>
#include <hip/hip_bf16.h>
#include <cstdint>

// MHRetention: x[4,4096,2048] ; Wq,Wk,Wv,Wu,Wo [2048,2048] (stored [in,out])
// q,k = relu(xW)/sqrt(128); u = silu(xWu); kv = sum_l k^T v per (b,h);
// o = srms_norm(q @ kv) * u ; y = o @ Wo
// N=16384 tokens, D=2048, H=16, dh=128.
//
// R11 = R8 (best, 979 us) + R9's verified helper improvements only.
// GEMM core frozen at R5 structure: six schedule experiments bracket it.

typedef __attribute__((ext_vector_type(8))) short short8;
typedef __attribute__((ext_vector_type(4))) float f32x4;

#define DEVI static __device__ __forceinline__

DEVI float bf2f(unsigned short u) {
    union { unsigned int i; float f; } w; w.i = ((unsigned int)u) << 16; return w.f;
}
DEVI unsigned short f2bf(float f) {
    union { float f; unsigned int i; } w; w.f = f;
    return (unsigned short)((w.i + 0x7fffu + ((w.i >> 16) & 1u)) >> 16);  // RNE
}

// global -> LDS direct DMA, 16B per lane. LDS dest is wave-uniform base + lane*16.
#define GLDS16(gp, lp) __builtin_amdgcn_global_load_lds( \
    (const __attribute__((address_space(1))) void*)(gp), \
    (__attribute__((address_space(3))) void*)(lp), 16, 0, 0)

// ---------------------------------------------------------------- dtype probe
__global__ void probe_dtype(const unsigned short* __restrict__ x, int* flag) {
    __shared__ int cnt;
    if (threadIdx.x == 0) cnt = 0;
    __syncthreads();
    int c = 0;
    for (int i = threadIdx.x; i < 4096; i += 256) {
        float a = fabsf(bf2f(x[i]));
        if (!(a <= 1e4f) || (a != 0.0f && a < 1e-4f)) ++c;
    }
    atomicAdd(&cnt, c);
    __syncthreads();
    if (threadIdx.x == 0) *flag = (cnt < 512) ? 1 : 0;
}

// ------------------------------------------------- weight transpose + convert
__global__ void wconvert(const void* __restrict__ Wq, const void* __restrict__ Wk,
                         const void* __restrict__ Wv, const void* __restrict__ Wu,
                         const void* __restrict__ Wo,
                         unsigned short* __restrict__ wt4,
                         unsigned short* __restrict__ wot,
                         const int* __restrict__ flag) {
    const int z = blockIdx.z;
    const void* W = (z == 0) ? Wq : (z == 1) ? Wk : (z == 2) ? Wv : (z == 3) ? Wu : Wo;
    const bool isbf = (*flag != 0);
    __shared__ float tile[32][33];
    const int j0 = blockIdx.x * 32, i0 = blockIdx.y * 32;
    const int tx = threadIdx.x, ty = threadIdx.y;  // (32,8)
#pragma unroll
    for (int r = 0; r < 4; ++r) {
        const int i = i0 + ty * 4 + r;
        float v;
        if (isbf) v = bf2f(((const unsigned short*)W)[i * 2048 + j0 + tx]);
        else      v = ((const float*)W)[i * 2048 + j0 + tx];
        tile[ty * 4 + r][tx] = v;
    }
    __syncthreads();
#pragma unroll
    for (int r = 0; r < 4; ++r) {
        const int j = j0 + ty * 4 + r;
        const unsigned short bv = f2bf(tile[tx][ty * 4 + r]);  // = W[i0+tx][j]
        if (z < 4) wt4[(long)(z * 2048 + j) * 2048 + i0 + tx] = bv;
        else       wot[(long)j * 2048 + i0 + tx] = bv;
    }
}

// ------------------------------------------------------------- x -> bf16
__global__ void xconvert(const void* __restrict__ X, unsigned short* __restrict__ xb,
                         const int* __restrict__ flag) {
    const bool isbf = (*flag != 0);
    const long i = (long)blockIdx.x * 256 + threadIdx.x;
    if (isbf) {
        ((uint4*)xb)[i] = ((const uint4*)X)[i];
    } else {
        const float4 f0 = ((const float4*)X)[2 * i];
        const float4 f1 = ((const float4*)X)[2 * i + 1];
        union { unsigned short us[8]; uint4 v; } o;
        o.us[0] = f2bf(f0.x); o.us[1] = f2bf(f0.y); o.us[2] = f2bf(f0.z); o.us[3] = f2bf(f0.w);
        o.us[4] = f2bf(f1.x); o.us[5] = f2bf(f1.y); o.us[6] = f2bf(f1.z); o.us[7] = f2bf(f1.w);
        ((uint4*)xb)[i] = o.v;
    }
}

// ---------------------------------------------------------------------------
// 256x256 GEMM core, register-double-buffered ring-4 pipeline (R5-exact,
// frozen). BK=32, 8 waves (2M x 4N), counted vmcnt(8), T2 swizzle, setprio.
// ---------------------------------------------------------------------------
DEVI void gemm_core(const unsigned short* __restrict__ Ag,   // + m0*2048
                    const unsigned short* __restrict__ Bg,   // + j0*2048
                    unsigned short* As, unsigned short* Bs,  // [4*8192] ushorts each
                    f32x4 acc[8][4], const int tid) {
    const int wave = tid >> 6, lane = tid & 63;
    const int wr = wave >> 2, wc = wave & 3;
    const int srow = tid >> 2;                       // 0..127 staging row
    const int lsl = (tid & 3) ^ ((srow >> 1) & 3);   // swizzled logical slot
    const unsigned short* ga0 = Ag + (long)srow * 2048 + lsl * 8;
    const unsigned short* ga1 = ga0 + 128 * 2048;
    const unsigned short* gb0 = Bg + (long)srow * 2048 + lsl * 8;
    const unsigned short* gb1 = gb0 + 128 * 2048;
    const int ldsb = wave * 512;                     // ushort off of wave's 1KB chunk

    // read side: physical slot = logical(lane>>4) ^ ((row>>1)&3)
    const int psl = ((lane >> 4) ^ (((lane & 15) >> 1) & 3)) * 8;
    const int abase = (wr * 128 + (lane & 15)) * 32 + psl;
    const int bbase = (wc * 64 + (lane & 15)) * 32 + psl;

#define ISSUE(tt) do { const int _b = (tt) & 3; const int _ko = (tt) * 32; \
    GLDS16(ga0 + _ko, As + _b * 8192 + ldsb); \
    GLDS16(ga1 + _ko, As + _b * 8192 + 4096 + ldsb); \
    GLDS16(gb0 + _ko, Bs + _b * 8192 + ldsb); \
    GLDS16(gb1 + _ko, Bs + _b * 8192 + 4096 + ldsb); } while (0)
#define RDFRAG(aX, bX, buf) do { \
    const unsigned short* _a = As + (buf) * 8192; \
    const unsigned short* _b = Bs + (buf) * 8192; \
    _Pragma("unroll") for (int fm = 0; fm < 8; ++fm) aX[fm] = *(const short8*)(_a + abase + fm * 512); \
    _Pragma("unroll") for (int fn = 0; fn < 4; ++fn) bX[fn] = *(const short8*)(_b + bbase + fn * 512); } while (0)
#define MFMACL(aX, bX) do { \
    __builtin_amdgcn_s_setprio(1); \
    _Pragma("unroll") for (int fm = 0; fm < 8; ++fm) \
    _Pragma("unroll") for (int fn = 0; fn < 4; ++fn) \
        acc[fm][fn] = __builtin_amdgcn_mfma_f32_16x16x32_bf16(aX[fm], bX[fn], acc[fm][fn], 0, 0, 0); \
    __builtin_amdgcn_s_setprio(0); } while (0)

    ISSUE(0); ISSUE(1); ISSUE(2); ISSUE(3);          // 16 loads outstanding
    asm volatile("s_waitcnt vmcnt(12)" ::: "memory"); // tile 0 resident
    asm volatile("s_barrier" ::: "memory");
    short8 aE[8], bE[4], aO[8], bO[4];
    RDFRAG(aE, bE, 0);                               // tile 0 -> even bank

    for (int tp = 0; tp < 32; ++tp) {
        const int t = 2 * tp;
        // ---- even body: compute tile t (E); read t+1 -> O; issue t+4
        asm volatile("s_waitcnt vmcnt(8)" ::: "memory");   // tile t+1 resident
        asm volatile("s_barrier" ::: "memory");            // all waves' DMA visible
        RDFRAG(aO, bO, (t + 1) & 3);
        asm volatile("s_waitcnt lgkmcnt(12)" ::: "memory"); // tile-t frags in regs
        { int ti = t + 4; if (ti >= 64) ti -= 64; ISSUE(ti); }  // -> buf[t&3]
        MFMACL(aE, bE);
        // ---- odd body: compute tile t+1 (O); read t+2 -> E; issue t+5
        asm volatile("s_waitcnt vmcnt(8)" ::: "memory");   // tile t+2 resident
        asm volatile("s_barrier" ::: "memory");
        { int tr = t + 2; if (tr > 63) tr = 63; RDFRAG(aE, bE, tr & 3); }
        asm volatile("s_waitcnt lgkmcnt(12)" ::: "memory");
        { int ti = t + 5; if (ti >= 64) ti -= 64; ISSUE(ti); }
        MFMACL(aO, bO);
    }
    asm volatile("s_waitcnt vmcnt(0) lgkmcnt(0)" ::: "memory");  // drain wrapped tails
#undef ISSUE
#undef RDFRAG
#undef MFMACL
}

// ---------------------------------------------- fused QKVU projection GEMM
__global__ __launch_bounds__(512, 2)
void gemm_qkvu(const unsigned short* __restrict__ Xb,
               const unsigned short* __restrict__ Wt4,
               unsigned short* __restrict__ Qb, unsigned short* __restrict__ Kb,
               unsigned short* __restrict__ Vb, unsigned short* __restrict__ Ub) {
    __shared__ unsigned short As[4 * 8192];
    __shared__ unsigned short Bs[4 * 8192];
    const int orig = blockIdx.x;                       // 0..2047
    const int flat = (orig & 7) * 256 + (orig >> 3);   // XCD owns 4 B-panels, m-fastest
    const int mt = flat & 63, nt = flat >> 6;          // 64 m-tiles, 32 n-tiles
    const long m0 = (long)mt * 256;
    const int tid = threadIdx.x;
    f32x4 acc[8][4] = {};

    gemm_core(Xb + m0 * 2048, Wt4 + (long)nt * 256 * 2048, As, Bs, acc, tid);

    const int wave = tid >> 6, lane = tid & 63;
    const int wr = wave >> 2, wc = wave & 3;
    const int seg = nt >> 3;                           // 0..3 -> Q,K,V,U
    unsigned short* outp = (seg == 0) ? Qb : (seg == 1) ? Kb : (seg == 2) ? Vb : Ub;
    const int cl0 = (nt & 7) * 256 + wc * 64;
#pragma unroll
    for (int fm = 0; fm < 8; ++fm) {
#pragma unroll
        for (int fn = 0; fn < 4; ++fn) {
            const int col = cl0 + fn * 16 + (lane & 15);
#pragma unroll
            for (int r = 0; r < 4; ++r) {
                const long row = m0 + wr * 128 + fm * 16 + ((lane >> 4) << 2) + r;
                float v = acc[fm][fn][r];
                if (seg <= 1)      v = fmaxf(v, 0.0f) * 0.08838834764831845f;  // relu/sqrt(128)
                else if (seg == 3) v = v / (1.0f + __expf(-v));                // silu
                outp[row * 2048 + col] = f2bf(v);
            }
        }
    }
}

// ------------------------------------------------------- output projection
__global__ __launch_bounds__(512, 2)
void gemm_out(const unsigned short* __restrict__ Obuf,
              const unsigned short* __restrict__ Wot,
              void* __restrict__ out, const int* __restrict__ flag) {
    __shared__ unsigned short As[4 * 8192];
    __shared__ unsigned short Bs[4 * 8192];
    const int orig = blockIdx.x;                       // 0..511
    const int flat = (orig & 7) * 64 + (orig >> 3);    // XCD owns 1 B-panel
    const int mt = flat & 63, nt = flat >> 6;          // 64 m-tiles, 8 n-tiles
    const long m0 = (long)mt * 256;
    const int j0 = nt * 256;
    const int tid = threadIdx.x;
    f32x4 acc[8][4] = {};

    gemm_core(Obuf + m0 * 2048, Wot + (long)j0 * 2048, As, Bs, acc, tid);

    const int wave = tid >> 6, lane = tid & 63;
    const int wr = wave >> 2, wc = wave & 3;
    const bool isbf = (*flag != 0);
#pragma unroll
    for (int fm = 0; fm < 8; ++fm) {
#pragma unroll
        for (int fn = 0; fn < 4; ++fn) {
            const int col = j0 + wc * 64 + fn * 16 + (lane & 15);
#pragma unroll
            for (int r = 0; r < 4; ++r) {
                const long row = m0 + wr * 128 + fm * 16 + ((lane >> 4) << 2) + r;
                const float v = acc[fm][fn][r];
                if (isbf) ((unsigned short*)out)[row * 2048 + col] = f2bf(v);
                else      ((float*)out)[row * 2048 + col] = v;
            }
        }
    }
}

// --------------------------------------------- KV state via MFMA (R9 version)
// KVt[dv][dk] = sum_l V[l,dv]*K[l,dk] per (b,h). Coalesced global reads
// (dk lane-fast, 256B rows), LDS [d][l] transposed with dual-field XOR swizzle.
__global__ void kv_accum(const unsigned short* __restrict__ Kb,
                         const unsigned short* __restrict__ Vb,
                         float* __restrict__ KVpart) {
    __shared__ unsigned short Kt[128 * 64];  // [dk][l], swizzled
    __shared__ unsigned short Vt[128 * 64];  // [dv][l], swizzled
    const int bh = blockIdx.x;      // 64
    const int chunk = blockIdx.y;   // 4 chunks of 1024 rows
    const int b = bh >> 4, h = bh & 15;
    const int t = threadIdx.x, wave = t >> 6, lane = t & 63;
    const int wr = wave >> 1, wc = wave & 1;
    const int dkg = t & 15;         // dk block: dkg*8 (lane-fast -> coalesced)
    const int l0 = (t >> 4) * 4;    // 4 consecutive l per thread
    const long gbase = ((long)b * 4096 + chunk * 1024) * 2048 + h * 128;
    f32x4 acc[4][4] = {};

    for (int tile = 0; tile < 16; ++tile) {
        __syncthreads();
        short8 kr[4], vr[4];
#pragma unroll
        for (int li = 0; li < 4; ++li) {
            const long go = gbase + (long)(tile * 64 + l0 + li) * 2048 + dkg * 8;
            kr[li] = *(const short8*)(Kb + go);
            vr[li] = *(const short8*)(Vb + go);
        }
#pragma unroll
        for (int i = 0; i < 8; ++i) {
            const int row = dkg * 8 + i;
            const int lin = row * 128 + l0 * 2;               // byte offset
            const int off = (lin ^ ((((row) ^ (row >> 3)) & 7) << 4)) >> 1;
            union { unsigned short us[4]; unsigned long long u; } pk, pv;
#pragma unroll
            for (int li = 0; li < 4; ++li) { pk.us[li] = (unsigned short)kr[li][i]; pv.us[li] = (unsigned short)vr[li][i]; }
            *(unsigned long long*)(Kt + off) = pk.u;
            *(unsigned long long*)(Vt + off) = pv.u;
        }
        __syncthreads();
#pragma unroll
        for (int ks = 0; ks < 2; ++ks) {
            const int kof = ks * 64 + (lane >> 4) * 16;
            short8 a[4], bfr[4];
#pragma unroll
            for (int f = 0; f < 4; ++f) {
                const int ra = wr * 64 + f * 16 + (lane & 15);
                const int rb = wc * 64 + f * 16 + (lane & 15);
                a[f]   = *(const short8*)(Vt + (((ra * 128 + kof) ^ ((((ra) ^ (ra >> 3)) & 7) << 4)) >> 1));
                bfr[f] = *(const short8*)(Kt + (((rb * 128 + kof) ^ ((((rb) ^ (rb >> 3)) & 7) << 4)) >> 1));
            }
#pragma unroll
            for (int fm = 0; fm < 4; ++fm)
#pragma unroll
                for (int fn = 0; fn < 4; ++fn)
                    acc[fm][fn] = __builtin_amdgcn_mfma_f32_16x16x32_bf16(a[fm], bfr[fn], acc[fm][fn], 0, 0, 0);
        }
    }
    float* dst = KVpart + ((long)chunk * 64 + bh) * 16384;
#pragma unroll
    for (int fm = 0; fm < 4; ++fm)
#pragma unroll
        for (int fn = 0; fn < 4; ++fn)
#pragma unroll
            for (int r = 0; r < 4; ++r) {
                const int dv = wr * 64 + fm * 16 + ((lane >> 4) << 2) + r;
                const int dk = wc * 64 + fn * 16 + (lane & 15);
                dst[dv * 128 + dk] = acc[fm][fn][r];
            }
}

// ------------------------------- sum partials, emit bf16 KV (hi only)
__global__ void kv_finalize(const float* __restrict__ KVpart,
                            unsigned short* __restrict__ KVhi) {
    const long base = ((long)blockIdx.x * 256 + threadIdx.x) * 4;
    float4 s0 = *(const float4*)(KVpart + base);
    const float4 s1 = *(const float4*)(KVpart + 1048576 + base);
    const float4 s2 = *(const float4*)(KVpart + 2097152 + base);
    const float4 s3 = *(const float4*)(KVpart + 3145728 + base);
    float s[4] = { s0.x + s1.x + s2.x + s3.x, s0.y + s1.y + s2.y + s3.y,
                   s0.z + s1.z + s2.z + s3.z, s0.w + s1.w + s2.w + s3.w };
    union { unsigned short us[4]; unsigned long long u; } hi;
#pragma unroll
    for (int j = 0; j < 4; ++j) hi.us[j] = f2bf(s[j]);
    *(unsigned long long*)(KVhi + base) = hi.u;
}

// ------------------------- O = Q @ KV, SRMS-norm over dh, * u -> Ob (R9 ver)
// Q,U staged via GLDS with pre-swizzled SOURCE cols (slot ^= (row>>2)&7)
// -> 4-way instead of 16-way LDS conflicts on frag reads; O staged into the
// dead Q buffer and stored as coalesced 16B rows.
__global__ void o_norm(const unsigned short* __restrict__ Qb,
                       const unsigned short* __restrict__ Ub,
                       const unsigned short* __restrict__ KVhi,
                       unsigned short* __restrict__ Ob) {
    __shared__ unsigned short Qs[128 * 128];  // Q tile; reused for O staging
    __shared__ unsigned short Us[128 * 128];  // U tile
    const int tid = threadIdx.x, wave = tid >> 6, lane = tid & 63;
    const int tile = blockIdx.x;   // 0..31
    const int bh = blockIdx.y;     // 0..63
    const int b = bh >> 4, h = bh & 15;
    const long n0 = (long)b * 4096 + tile * 128;

    const int qrow = tid >> 4;          // 0..15
#pragma unroll
    for (int i = 0; i < 8; ++i) {
        const int row = i * 16 + qrow;
        const int scol = ((tid & 15) ^ ((row >> 2) & 7)) * 8;  // pre-swizzled source
        GLDS16(Qb + (n0 + row) * 2048 + h * 128 + scol, Qs + i * 2048 + wave * 512);
        GLDS16(Ub + (n0 + row) * 2048 + h * 128 + scol, Us + i * 2048 + wave * 512);
    }
    __syncthreads();

    const unsigned short* KH = KVhi + (long)bh * 16384;
    f32x4 acc[2][8] = {};
    const int arow0 = wave * 32 + (lane & 15);
    const int arow1 = arow0 + 16;
    const int fq0 = (arow0 >> 2) & 7;
    const int fq1 = (arow1 >> 2) & 7;
#pragma unroll
    for (int kk = 0; kk < 4; ++kk) {
        const short8 a0 = *(const short8*)(Qs + arow0 * 128 + (((kk * 4 + (lane >> 4)) ^ fq0) << 3));
        const short8 a1 = *(const short8*)(Qs + arow1 * 128 + (((kk * 4 + (lane >> 4)) ^ fq1) << 3));
#pragma unroll
        for (int fn = 0; fn < 8; ++fn) {
            const int bo = (fn * 16 + (lane & 15)) * 128 + kk * 32 + (lane >> 4) * 8;
            const short8 bhi = *(const short8*)(KH + bo);
            acc[0][fn] = __builtin_amdgcn_mfma_f32_16x16x32_bf16(a0, bhi, acc[0][fn], 0, 0, 0);
            acc[1][fn] = __builtin_amdgcn_mfma_f32_16x16x32_bf16(a1, bhi, acc[1][fn], 0, 0, 0);
        }
    }

#pragma unroll
    for (int fm = 0; fm < 2; ++fm) {
#pragma unroll
        for (int r = 0; r < 4; ++r) {
            float ssq = 0.0f;
#pragma unroll
            for (int fn = 0; fn < 8; ++fn) { const float v = acc[fm][fn][r]; ssq += v * v; }
            ssq += __shfl_xor(ssq, 1);
            ssq += __shfl_xor(ssq, 2);
            ssq += __shfl_xor(ssq, 4);
            ssq += __shfl_xor(ssq, 8);
            const float nrm = fmaxf(sqrtf(ssq) * 0.08838834764831845f, 1e-12f);
            const float scl = 1.0f / nrm;
            const int lrow = wave * 32 + fm * 16 + ((lane >> 4) << 2) + r;
            const int fr = (lrow >> 2) & 7;
#pragma unroll
            for (int fn = 0; fn < 8; ++fn) {
                const int col = fn * 16 + (lane & 15);
                const int sofs = lrow * 128 + ((((col >> 3) ^ fr) << 3) | (col & 7));
                const float uv = bf2f(Us[sofs]);
                Qs[sofs] = f2bf(acc[fm][fn][r] * scl * uv);  // own-band overwrite
            }
        }
    }
    __syncthreads();
    // coalesced store: 8 passes x (256 threads x 16B)
#pragma unroll
    for (int p = 0; p < 8; ++p) {
        const int row = p * 16 + (tid >> 4);
        const int slotL = tid & 15;
        const uint4 val = *(const uint4*)(Qs + row * 128 + slotL * 8);
        const int gcol = ((slotL ^ ((row >> 2) & 7)) & 15) * 8;
        *(uint4*)(Ob + (n0 + row) * 2048 + h * 128 + gcol) = val;
    }
}

// ---------------------------------------------------------------- launcher
extern "C" void kernel_launch(void* const* d_in, const int* in_sizes, int n_in,
                              void* d_out, int out_size, void* d_ws, size_t ws_size,
                              hipStream_t stream) {
    (void)in_sizes; (void)n_in; (void)out_size; (void)ws_size;
    char* ws = (char*)d_ws;
    unsigned short* Xb  = (unsigned short*)(ws + 0);           // 64 MB
    unsigned short* Wt4 = (unsigned short*)(ws + 67108864);    // 32 MB
    unsigned short* Wot = (unsigned short*)(ws + 100663296);   //  8 MB
    unsigned short* Qb  = (unsigned short*)(ws + 109051904);   // 64 MB
    unsigned short* Kb  = (unsigned short*)(ws + 176160768);   // 64 MB
    unsigned short* Vb  = (unsigned short*)(ws + 243269632);   // 64 MB
    unsigned short* Ub  = (unsigned short*)(ws + 310378496);   // 64 MB
    int*            flag= (int*)(ws + 381681664);              //  4 B
    // regions reused after their producers are done:
    float*          KVpart = (float*)Wt4;                       // 16 MB (Wt4 dead after gemm_qkvu)
    unsigned short* KVhi   = (unsigned short*)(ws + 67108864 + 16777216);  // 2 MB
    unsigned short* Ob     = Xb;                                // Xb dead after gemm_qkvu

    probe_dtype<<<1, 256, 0, stream>>>((const unsigned short*)d_in[0], flag);
    wconvert<<<dim3(64, 64, 5), dim3(32, 8), 0, stream>>>(d_in[1], d_in[2], d_in[3],
                                                          d_in[4], d_in[5], Wt4, Wot, flag);
    xconvert<<<16384, 256, 0, stream>>>(d_in[0], Xb, flag);
    gemm_qkvu<<<2048, 512, 0, stream>>>(Xb, Wt4, Qb, Kb, Vb, Ub);
    kv_accum<<<dim3(64, 4), 256, 0, stream>>>(Kb, Vb, KVpart);
    kv_finalize<<<1024, 256, 0, stream>>>(KVpart, KVhi);
    o_norm<<<dim3(32, 64), 256, 0, stream>>>(Qb, Ub, KVhi, Ob);
    gemm_out<<<512, 512, 0, stream>>>(Ob, Wot, d_out, flag);
}

// Round 12
// 969.284 us; speedup vs baseline: 1.1734x; 1.0244x over previous
//
#include <hip/hip_runtime.h>
#include <hip/hip_bf16.h>
#include <cstdint>

// MHRetention: x[4,4096,2048] ; Wq,Wk,Wv,Wu,Wo [2048,2048] (stored [in,out])
// q,k = relu(xW)/sqrt(128); u = silu(xWu); kv = sum_l k^T v per (b,h);
// o = srms_norm(q @ kv) * u ; y = o @ Wo
// N=16384 tokens, D=2048, H=16, dh=128.
//
// R12 = R11 + kv_accum occupancy fix (8 L-chunks -> 2 blocks/CU).
// GEMM core frozen at R5 structure (six experiments bracket it).

typedef __attribute__((ext_vector_type(8))) short short8;
typedef __attribute__((ext_vector_type(4))) float f32x4;

#define DEVI static __device__ __forceinline__

DEVI float bf2f(unsigned short u) {
    union { unsigned int i; float f; } w; w.i = ((unsigned int)u) << 16; return w.f;
}
DEVI unsigned short f2bf(float f) {
    union { float f; unsigned int i; } w; w.f = f;
    return (unsigned short)((w.i + 0x7fffu + ((w.i >> 16) & 1u)) >> 16);  // RNE
}

// global -> LDS direct DMA, 16B per lane. LDS dest is wave-uniform base + lane*16.
#define GLDS16(gp, lp) __builtin_amdgcn_global_load_lds( \
    (const __attribute__((address_space(1))) void*)(gp), \
    (__attribute__((address_space(3))) void*)(lp), 16, 0, 0)

// ---------------------------------------------------------------- dtype probe
__global__ void probe_dtype(const unsigned short* __restrict__ x, int* flag) {
    __shared__ int cnt;
    if (threadIdx.x == 0) cnt = 0;
    __syncthreads();
    int c = 0;
    for (int i = threadIdx.x; i < 4096; i += 256) {
        float a = fabsf(bf2f(x[i]));
        if (!(a <= 1e4f) || (a != 0.0f && a < 1e-4f)) ++c;
    }
    atomicAdd(&cnt, c);
    __syncthreads();
    if (threadIdx.x == 0) *flag = (cnt < 512) ? 1 : 0;
}

// ------------------------------------------------- weight transpose + convert
__global__ void wconvert(const void* __restrict__ Wq, const void* __restrict__ Wk,
                         const void* __restrict__ Wv, const void* __restrict__ Wu,
                         const void* __restrict__ Wo,
                         unsigned short* __restrict__ wt4,
                         unsigned short* __restrict__ wot,
                         const int* __restrict__ flag) {
    const int z = blockIdx.z;
    const void* W = (z == 0) ? Wq : (z == 1) ? Wk : (z == 2) ? Wv : (z == 3) ? Wu : Wo;
    const bool isbf = (*flag != 0);
    __shared__ float tile[32][33];
    const int j0 = blockIdx.x * 32, i0 = blockIdx.y * 32;
    const int tx = threadIdx.x, ty = threadIdx.y;  // (32,8)
#pragma unroll
    for (int r = 0; r < 4; ++r) {
        const int i = i0 + ty * 4 + r;
        float v;
        if (isbf) v = bf2f(((const unsigned short*)W)[i * 2048 + j0 + tx]);
        else      v = ((const float*)W)[i * 2048 + j0 + tx];
        tile[ty * 4 + r][tx] = v;
    }
    __syncthreads();
#pragma unroll
    for (int r = 0; r < 4; ++r) {
        const int j = j0 + ty * 4 + r;
        const unsigned short bv = f2bf(tile[tx][ty * 4 + r]);  // = W[i0+tx][j]
        if (z < 4) wt4[(long)(z * 2048 + j) * 2048 + i0 + tx] = bv;
        else       wot[(long)j * 2048 + i0 + tx] = bv;
    }
}

// ------------------------------------------------------------- x -> bf16
__global__ void xconvert(const void* __restrict__ X, unsigned short* __restrict__ xb,
                         const int* __restrict__ flag) {
    const bool isbf = (*flag != 0);
    const long i = (long)blockIdx.x * 256 + threadIdx.x;
    if (isbf) {
        ((uint4*)xb)[i] = ((const uint4*)X)[i];
    } else {
        const float4 f0 = ((const float4*)X)[2 * i];
        const float4 f1 = ((const float4*)X)[2 * i + 1];
        union { unsigned short us[8]; uint4 v; } o;
        o.us[0] = f2bf(f0.x); o.us[1] = f2bf(f0.y); o.us[2] = f2bf(f0.z); o.us[3] = f2bf(f0.w);
        o.us[4] = f2bf(f1.x); o.us[5] = f2bf(f1.y); o.us[6] = f2bf(f1.z); o.us[7] = f2bf(f1.w);
        ((uint4*)xb)[i] = o.v;
    }
}

// ---------------------------------------------------------------------------
// 256x256 GEMM core, register-double-buffered ring-4 pipeline (R5-exact,
// frozen). BK=32, 8 waves (2M x 4N), counted vmcnt(8), T2 swizzle, setprio.
// ---------------------------------------------------------------------------
DEVI void gemm_core(const unsigned short* __restrict__ Ag,   // + m0*2048
                    const unsigned short* __restrict__ Bg,   // + j0*2048
                    unsigned short* As, unsigned short* Bs,  // [4*8192] ushorts each
                    f32x4 acc[8][4], const int tid) {
    const int wave = tid >> 6, lane = tid & 63;
    const int wr = wave >> 2, wc = wave & 3;
    const int srow = tid >> 2;                       // 0..127 staging row
    const int lsl = (tid & 3) ^ ((srow >> 1) & 3);   // swizzled logical slot
    const unsigned short* ga0 = Ag + (long)srow * 2048 + lsl * 8;
    const unsigned short* ga1 = ga0 + 128 * 2048;
    const unsigned short* gb0 = Bg + (long)srow * 2048 + lsl * 8;
    const unsigned short* gb1 = gb0 + 128 * 2048;
    const int ldsb = wave * 512;                     // ushort off of wave's 1KB chunk

    // read side: physical slot = logical(lane>>4) ^ ((row>>1)&3)
    const int psl = ((lane >> 4) ^ (((lane & 15) >> 1) & 3)) * 8;
    const int abase = (wr * 128 + (lane & 15)) * 32 + psl;
    const int bbase = (wc * 64 + (lane & 15)) * 32 + psl;

#define ISSUE(tt) do { const int _b = (tt) & 3; const int _ko = (tt) * 32; \
    GLDS16(ga0 + _ko, As + _b * 8192 + ldsb); \
    GLDS16(ga1 + _ko, As + _b * 8192 + 4096 + ldsb); \
    GLDS16(gb0 + _ko, Bs + _b * 8192 + ldsb); \
    GLDS16(gb1 + _ko, Bs + _b * 8192 + 4096 + ldsb); } while (0)
#define RDFRAG(aX, bX, buf) do { \
    const unsigned short* _a = As + (buf) * 8192; \
    const unsigned short* _b = Bs + (buf) * 8192; \
    _Pragma("unroll") for (int fm = 0; fm < 8; ++fm) aX[fm] = *(const short8*)(_a + abase + fm * 512); \
    _Pragma("unroll") for (int fn = 0; fn < 4; ++fn) bX[fn] = *(const short8*)(_b + bbase + fn * 512); } while (0)
#define MFMACL(aX, bX) do { \
    __builtin_amdgcn_s_setprio(1); \
    _Pragma("unroll") for (int fm = 0; fm < 8; ++fm) \
    _Pragma("unroll") for (int fn = 0; fn < 4; ++fn) \
        acc[fm][fn] = __builtin_amdgcn_mfma_f32_16x16x32_bf16(aX[fm], bX[fn], acc[fm][fn], 0, 0, 0); \
    __builtin_amdgcn_s_setprio(0); } while (0)

    ISSUE(0); ISSUE(1); ISSUE(2); ISSUE(3);          // 16 loads outstanding
    asm volatile("s_waitcnt vmcnt(12)" ::: "memory"); // tile 0 resident
    asm volatile("s_barrier" ::: "memory");
    short8 aE[8], bE[4], aO[8], bO[4];
    RDFRAG(aE, bE, 0);                               // tile 0 -> even bank

    for (int tp = 0; tp < 32; ++tp) {
        const int t = 2 * tp;
        // ---- even body: compute tile t (E); read t+1 -> O; issue t+4
        asm volatile("s_waitcnt vmcnt(8)" ::: "memory");   // tile t+1 resident
        asm volatile("s_barrier" ::: "memory");            // all waves' DMA visible
        RDFRAG(aO, bO, (t + 1) & 3);
        asm volatile("s_waitcnt lgkmcnt(12)" ::: "memory"); // tile-t frags in regs
        { int ti = t + 4; if (ti >= 64) ti -= 64; ISSUE(ti); }  // -> buf[t&3]
        MFMACL(aE, bE);
        // ---- odd body: compute tile t+1 (O); read t+2 -> E; issue t+5
        asm volatile("s_waitcnt vmcnt(8)" ::: "memory");   // tile t+2 resident
        asm volatile("s_barrier" ::: "memory");
        { int tr = t + 2; if (tr > 63) tr = 63; RDFRAG(aE, bE, tr & 3); }
        asm volatile("s_waitcnt lgkmcnt(12)" ::: "memory");
        { int ti = t + 5; if (ti >= 64) ti -= 64; ISSUE(ti); }
        MFMACL(aO, bO);
    }
    asm volatile("s_waitcnt vmcnt(0) lgkmcnt(0)" ::: "memory");  // drain wrapped tails
#undef ISSUE
#undef RDFRAG
#undef MFMACL
}

// ---------------------------------------------- fused QKVU projection GEMM
__global__ __launch_bounds__(512, 2)
void gemm_qkvu(const unsigned short* __restrict__ Xb,
               const unsigned short* __restrict__ Wt4,
               unsigned short* __restrict__ Qb, unsigned short* __restrict__ Kb,
               unsigned short* __restrict__ Vb, unsigned short* __restrict__ Ub) {
    __shared__ unsigned short As[4 * 8192];
    __shared__ unsigned short Bs[4 * 8192];
    const int orig = blockIdx.x;                       // 0..2047
    const int flat = (orig & 7) * 256 + (orig >> 3);   // XCD owns 4 B-panels, m-fastest
    const int mt = flat & 63, nt = flat >> 6;          // 64 m-tiles, 32 n-tiles
    const long m0 = (long)mt * 256;
    const int tid = threadIdx.x;
    f32x4 acc[8][4] = {};

    gemm_core(Xb + m0 * 2048, Wt4 + (long)nt * 256 * 2048, As, Bs, acc, tid);

    const int wave = tid >> 6, lane = tid & 63;
    const int wr = wave >> 2, wc = wave & 3;
    const int seg = nt >> 3;                           // 0..3 -> Q,K,V,U
    unsigned short* outp = (seg == 0) ? Qb : (seg == 1) ? Kb : (seg == 2) ? Vb : Ub;
    const int cl0 = (nt & 7) * 256 + wc * 64;
#pragma unroll
    for (int fm = 0; fm < 8; ++fm) {
#pragma unroll
        for (int fn = 0; fn < 4; ++fn) {
            const int col = cl0 + fn * 16 + (lane & 15);
#pragma unroll
            for (int r = 0; r < 4; ++r) {
                const long row = m0 + wr * 128 + fm * 16 + ((lane >> 4) << 2) + r;
                float v = acc[fm][fn][r];
                if (seg <= 1)      v = fmaxf(v, 0.0f) * 0.08838834764831845f;  // relu/sqrt(128)
                else if (seg == 3) v = v / (1.0f + __expf(-v));                // silu
                outp[row * 2048 + col] = f2bf(v);
            }
        }
    }
}

// ------------------------------------------------------- output projection
__global__ __launch_bounds__(512, 2)
void gemm_out(const unsigned short* __restrict__ Obuf,
              const unsigned short* __restrict__ Wot,
              void* __restrict__ out, const int* __restrict__ flag) {
    __shared__ unsigned short As[4 * 8192];
    __shared__ unsigned short Bs[4 * 8192];
    const int orig = blockIdx.x;                       // 0..511
    const int flat = (orig & 7) * 64 + (orig >> 3);    // XCD owns 1 B-panel
    const int mt = flat & 63, nt = flat >> 6;          // 64 m-tiles, 8 n-tiles
    const long m0 = (long)mt * 256;
    const int j0 = nt * 256;
    const int tid = threadIdx.x;
    f32x4 acc[8][4] = {};

    gemm_core(Obuf + m0 * 2048, Wot + (long)j0 * 2048, As, Bs, acc, tid);

    const int wave = tid >> 6, lane = tid & 63;
    const int wr = wave >> 2, wc = wave & 3;
    const bool isbf = (*flag != 0);
#pragma unroll
    for (int fm = 0; fm < 8; ++fm) {
#pragma unroll
        for (int fn = 0; fn < 4; ++fn) {
            const int col = j0 + wc * 64 + fn * 16 + (lane & 15);
#pragma unroll
            for (int r = 0; r < 4; ++r) {
                const long row = m0 + wr * 128 + fm * 16 + ((lane >> 4) << 2) + r;
                const float v = acc[fm][fn][r];
                if (isbf) ((unsigned short*)out)[row * 2048 + col] = f2bf(v);
                else      ((float*)out)[row * 2048 + col] = v;
            }
        }
    }
}

// --------------------------------------------- KV state via MFMA (R12: 8 chunks)
// KVt[dv][dk] = sum_l V[l,dv]*K[l,dk] per (b,h). Coalesced global reads
// (dk lane-fast, 256B rows), LDS [d][l] transposed dual-XOR swizzle.
// 8 L-chunks of 512 rows -> 512 blocks (2 blocks/CU, 2 waves/SIMD).
__global__ void kv_accum(const unsigned short* __restrict__ Kb,
                         const unsigned short* __restrict__ Vb,
                         float* __restrict__ KVpart) {
    __shared__ unsigned short Kt[128 * 64];  // [dk][l], swizzled
    __shared__ unsigned short Vt[128 * 64];  // [dv][l], swizzled
    const int bh = blockIdx.x;      // 64
    const int chunk = blockIdx.y;   // 8 chunks of 512 rows
    const int b = bh >> 4, h = bh & 15;
    const int t = threadIdx.x, wave = t >> 6, lane = t & 63;
    const int wr = wave >> 1, wc = wave & 1;
    const int dkg = t & 15;         // dk block: dkg*8 (lane-fast -> coalesced)
    const int l0 = (t >> 4) * 4;    // 4 consecutive l per thread
    const long gbase = ((long)b * 4096 + chunk * 512) * 2048 + h * 128;
    f32x4 acc[4][4] = {};

    for (int tile = 0; tile < 8; ++tile) {
        __syncthreads();
        short8 kr[4], vr[4];
#pragma unroll
        for (int li = 0; li < 4; ++li) {
            const long go = gbase + (long)(tile * 64 + l0 + li) * 2048 + dkg * 8;
            kr[li] = *(const short8*)(Kb + go);
            vr[li] = *(const short8*)(Vb + go);
        }
#pragma unroll
        for (int i = 0; i < 8; ++i) {
            const int row = dkg * 8 + i;
            const int lin = row * 128 + l0 * 2;               // byte offset
            const int off = (lin ^ ((((row) ^ (row >> 3)) & 7) << 4)) >> 1;
            union { unsigned short us[4]; unsigned long long u; } pk, pv;
#pragma unroll
            for (int li = 0; li < 4; ++li) { pk.us[li] = (unsigned short)kr[li][i]; pv.us[li] = (unsigned short)vr[li][i]; }
            *(unsigned long long*)(Kt + off) = pk.u;
            *(unsigned long long*)(Vt + off) = pv.u;
        }
        __syncthreads();
#pragma unroll
        for (int ks = 0; ks < 2; ++ks) {
            const int kof = ks * 64 + (lane >> 4) * 16;
            short8 a[4], bfr[4];
#pragma unroll
            for (int f = 0; f < 4; ++f) {
                const int ra = wr * 64 + f * 16 + (lane & 15);
                const int rb = wc * 64 + f * 16 + (lane & 15);
                a[f]   = *(const short8*)(Vt + (((ra * 128 + kof) ^ ((((ra) ^ (ra >> 3)) & 7) << 4)) >> 1));
                bfr[f] = *(const short8*)(Kt + (((rb * 128 + kof) ^ ((((rb) ^ (rb >> 3)) & 7) << 4)) >> 1));
            }
#pragma unroll
            for (int fm = 0; fm < 4; ++fm)
#pragma unroll
                for (int fn = 0; fn < 4; ++fn)
                    acc[fm][fn] = __builtin_amdgcn_mfma_f32_16x16x32_bf16(a[fm], bfr[fn], acc[fm][fn], 0, 0, 0);
        }
    }
    float* dst = KVpart + ((long)chunk * 64 + bh) * 16384;
#pragma unroll
    for (int fm = 0; fm < 4; ++fm)
#pragma unroll
        for (int fn = 0; fn < 4; ++fn)
#pragma unroll
            for (int r = 0; r < 4; ++r) {
                const int dv = wr * 64 + fm * 16 + ((lane >> 4) << 2) + r;
                const int dk = wc * 64 + fn * 16 + (lane & 15);
                dst[dv * 128 + dk] = acc[fm][fn][r];
            }
}

// ------------------------------- sum 8 partials, emit bf16 KV (hi only)
__global__ void kv_finalize(const float* __restrict__ KVpart,
                            unsigned short* __restrict__ KVhi) {
    const long base = ((long)blockIdx.x * 256 + threadIdx.x) * 4;
    float s[4] = {0.0f, 0.0f, 0.0f, 0.0f};
#pragma unroll
    for (int c = 0; c < 8; ++c) {
        const float4 p = *(const float4*)(KVpart + (long)c * 1048576 + base);
        s[0] += p.x; s[1] += p.y; s[2] += p.z; s[3] += p.w;
    }
    union { unsigned short us[4]; unsigned long long u; } hi;
#pragma unroll
    for (int j = 0; j < 4; ++j) hi.us[j] = f2bf(s[j]);
    *(unsigned long long*)(KVhi + base) = hi.u;
}

// ------------------------- O = Q @ KV, SRMS-norm over dh, * u -> Ob
// Q,U staged via GLDS with pre-swizzled SOURCE cols (slot ^= (row>>2)&7);
// O staged into the dead Q buffer and stored as coalesced 16B rows.
__global__ void o_norm(const unsigned short* __restrict__ Qb,
                       const unsigned short* __restrict__ Ub,
                       const unsigned short* __restrict__ KVhi,
                       unsigned short* __restrict__ Ob) {
    __shared__ unsigned short Qs[128 * 128];  // Q tile; reused for O staging
    __shared__ unsigned short Us[128 * 128];  // U tile
    const int tid = threadIdx.x, wave = tid >> 6, lane = tid & 63;
    const int tile = blockIdx.x;   // 0..31
    const int bh = blockIdx.y;     // 0..63
    const int b = bh >> 4, h = bh & 15;
    const long n0 = (long)b * 4096 + tile * 128;

    const int qrow = tid >> 4;          // 0..15
#pragma unroll
    for (int i = 0; i < 8; ++i) {
        const int row = i * 16 + qrow;
        const int scol = ((tid & 15) ^ ((row >> 2) & 7)) * 8;  // pre-swizzled source
        GLDS16(Qb + (n0 + row) * 2048 + h * 128 + scol, Qs + i * 2048 + wave * 512);
        GLDS16(Ub + (n0 + row) * 2048 + h * 128 + scol, Us + i * 2048 + wave * 512);
    }
    __syncthreads();

    const unsigned short* KH = KVhi + (long)bh * 16384;
    f32x4 acc[2][8] = {};
    const int arow0 = wave * 32 + (lane & 15);
    const int arow1 = arow0 + 16;
    const int fq0 = (arow0 >> 2) & 7;
    const int fq1 = (arow1 >> 2) & 7;
#pragma unroll
    for (int kk = 0; kk < 4; ++kk) {
        const short8 a0 = *(const short8*)(Qs + arow0 * 128 + (((kk * 4 + (lane >> 4)) ^ fq0) << 3));
        const short8 a1 = *(const short8*)(Qs + arow1 * 128 + (((kk * 4 + (lane >> 4)) ^ fq1) << 3));
#pragma unroll
        for (int fn = 0; fn < 8; ++fn) {
            const int bo = (fn * 16 + (lane & 15)) * 128 + kk * 32 + (lane >> 4) * 8;
            const short8 bhi = *(const short8*)(KH + bo);
            acc[0][fn] = __builtin_amdgcn_mfma_f32_16x16x32_bf16(a0, bhi, acc[0][fn], 0, 0, 0);
            acc[1][fn] = __builtin_amdgcn_mfma_f32_16x16x32_bf16(a1, bhi, acc[1][fn], 0, 0, 0);
        }
    }

#pragma unroll
    for (int fm = 0; fm < 2; ++fm) {
#pragma unroll
        for (int r = 0; r < 4; ++r) {
            float ssq = 0.0f;
#pragma unroll
            for (int fn = 0; fn < 8; ++fn) { const float v = acc[fm][fn][r]; ssq += v * v; }
            ssq += __shfl_xor(ssq, 1);
            ssq += __shfl_xor(ssq, 2);
            ssq += __shfl_xor(ssq, 4);
            ssq += __shfl_xor(ssq, 8);
            const float nrm = fmaxf(sqrtf(ssq) * 0.08838834764831845f, 1e-12f);
            const float scl = 1.0f / nrm;
            const int lrow = wave * 32 + fm * 16 + ((lane >> 4) << 2) + r;
            const int fr = (lrow >> 2) & 7;
#pragma unroll
            for (int fn = 0; fn < 8; ++fn) {
                const int col = fn * 16 + (lane & 15);
                const int sofs = lrow * 128 + ((((col >> 3) ^ fr) << 3) | (col & 7));
                const float uv = bf2f(Us[sofs]);
                Qs[sofs] = f2bf(acc[fm][fn][r] * scl * uv);  // own-band overwrite
            }
        }
    }
    __syncthreads();
    // coalesced store: 8 passes x (256 threads x 16B)
#pragma unroll
    for (int p = 0; p < 8; ++p) {
        const int row = p * 16 + (tid >> 4);
        const int slotL = tid & 15;
        const uint4 val = *(const uint4*)(Qs + row * 128 + slotL * 8);
        const int gcol = ((slotL ^ ((row >> 2) & 7)) & 15) * 8;
        *(uint4*)(Ob + (n0 + row) * 2048 + h * 128 + gcol) = val;
    }
}

// ---------------------------------------------------------------- launcher
extern "C" void kernel_launch(void* const* d_in, const int* in_sizes, int n_in,
                              void* d_out, int out_size, void* d_ws, size_t ws_size,
                              hipStream_t stream) {
    (void)in_sizes; (void)n_in; (void)out_size; (void)ws_size;
    char* ws = (char*)d_ws;
    unsigned short* Xb  = (unsigned short*)(ws + 0);           // 64 MB
    unsigned short* Wt4 = (unsigned short*)(ws + 67108864);    // 32 MB
    unsigned short* Wot = (unsigned short*)(ws + 100663296);   //  8 MB
    unsigned short* Qb  = (unsigned short*)(ws + 109051904);   // 64 MB
    unsigned short* Kb  = (unsigned short*)(ws + 176160768);   // 64 MB
    unsigned short* Vb  = (unsigned short*)(ws + 243269632);   // 64 MB
    unsigned short* Ub  = (unsigned short*)(ws + 310378496);   // 64 MB
    int*            flag= (int*)(ws + 381681664);              //  4 B
    // regions reused after their producers are done:
    float*          KVpart = (float*)Wt4;                       // 32 MB (Wt4 dead after gemm_qkvu)
    unsigned short* KVhi   = (unsigned short*)(ws + 100663296); // 2 MB (Wot dead after... no!)
    unsigned short* Ob     = Xb;                                // Xb dead after gemm_qkvu

    // NOTE: Wot is still needed by gemm_out -> place KVhi in the flag page
    // region instead (after the 382MB high-water mark there is no guarantee),
    // so carve KVhi from the tail of Qb's region? Qb is needed by o_norm.
    // Safe spot: Ub region tail is needed too. Use the gap after flag:
    // KVpart now occupies all 32MB of Wt4; KVhi (2MB) goes after flag page.
    KVhi = (unsigned short*)(ws + 381681664 + 4096);            // 2 MB, after flag

    probe_dtype<<<1, 256, 0, stream>>>((const unsigned short*)d_in[0], flag);
    wconvert<<<dim3(64, 64, 5), dim3(32, 8), 0, stream>>>(d_in[1], d_in[2], d_in[3],
                                                          d_in[4], d_in[5], Wt4, Wot, flag);
    xconvert<<<16384, 256, 0, stream>>>(d_in[0], Xb, flag);
    gemm_qkvu<<<2048, 512, 0, stream>>>(Xb, Wt4, Qb, Kb, Vb, Ub);
    kv_accum<<<dim3(64, 8), 256, 0, stream>>>(Kb, Vb, KVpart);
    kv_finalize<<<1024, 256, 0, stream>>>(KVpart, KVhi);
    o_norm<<<dim3(32, 64), 256, 0, stream>>>(Qb, Ub, KVhi, Ob);
    gemm_out<<<512, 512, 0, stream>>>(Ob, Wot, d_out, flag);
}